// Round 1
// baseline (6486.900 us; speedup 1.0000x reference)
//
#include <hip/hip_runtime.h>
#include <hip/hip_bf16.h>

// LSTM: N=64 batch, T=512 steps, D=1024, H=1024.
// Strategy (round 1, correctness-first):
//   prep_weights: Wt[a_col][k] = bf16 of [Wx;Wh][k][a_col]   (4096 x 2048, 16 MB, = B^T layout)
//   prep_state:   h buffer <- bf16(h0), c <- 0
//   lstm_step x512: A_t = [x_t | h_{t-1}] @ Wt^T + b, gates, write h_t (fp32 to out, bf16 to hbuf)
// Grid 256 WGs = 4 batch-groups(16 rows) x 64 col-groups(16 h-cols). Wave w computes gate w
// via mfma_f32_16x16x32_bf16, K=2048 staged into LDS in two 1024 halves (LDS 37 KB).

#define T_T 512
#define KTOT 2048

typedef short bf16x8 __attribute__((ext_vector_type(8)));   // 8 bf16 (4 VGPRs)
typedef float f32x4 __attribute__((ext_vector_type(4)));

union B8U { uint4 u; bf16x8 v; };
union P4 { __hip_bfloat16 h[4]; uint2 u; };

__global__ __launch_bounds__(256) void prep_weights(const float* __restrict__ Wx,
                                                    const float* __restrict__ Wh,
                                                    __hip_bfloat16* __restrict__ Wt) {
  __shared__ float tile[64][65];
  int kb = blockIdx.x & 31;   // 32 k-tiles of 64  (K=2048: first 16 from Wx, last 16 from Wh)
  int cb = blockIdx.x >> 5;   // 64 c-tiles of 64  (4096 a_cols)
  int k0 = kb << 6, c0 = cb << 6;
  const float* W = (k0 < 1024) ? Wx : Wh;
  int kr0 = k0 & 1023;
  int tid = threadIdx.x;
  int f4 = tid & 15;          // float4 index within 64-col row
  int i0 = tid >> 4;          // k row within tile
  for (int p = 0; p < 4; ++p) {
    int i = i0 + (p << 4);
    float4 v = *(const float4*)(W + (size_t)(kr0 + i) * 4096 + c0 + (f4 << 2));
    tile[(f4 << 2) + 0][i] = v.x;
    tile[(f4 << 2) + 1][i] = v.y;
    tile[(f4 << 2) + 2][i] = v.z;
    tile[(f4 << 2) + 3][i] = v.w;
  }
  __syncthreads();
  for (int p = 0; p < 16; ++p) {
    int idx = (p << 8) + tid;
    int kl = idx & 63, cl = idx >> 6;     // consecutive tid -> consecutive k: coalesced
    Wt[(size_t)(c0 + cl) * KTOT + k0 + kl] = __float2bfloat16(tile[cl][kl]);
  }
}

__global__ __launch_bounds__(256) void prep_state(const float* __restrict__ h0,
                                                  __hip_bfloat16* __restrict__ hb,
                                                  float* __restrict__ cb) {
  int i = blockIdx.x * 256 + threadIdx.x;   // 65536 elements
  hb[i] = __float2bfloat16(h0[i]);
  cb[i] = 0.f;
}

__global__ __launch_bounds__(256) void lstm_step(
    const float* __restrict__ x, const float* __restrict__ bias,
    const __hip_bfloat16* __restrict__ Wt,
    const __hip_bfloat16* __restrict__ hprev,
    __hip_bfloat16* __restrict__ hnext,
    float* __restrict__ cbuf, float* __restrict__ out, int t)
{
  // row stride 1032 bf16 = 2064 B: 16B-aligned, bank shift 4/row -> <=2-way conflicts (free)
  __shared__ __align__(16) __hip_bfloat16 Alds[16][1032];
  __shared__ float gtile[4][16][17];

  const int tid = threadIdx.x;
  const int cgrp = blockIdx.x & 63;   // h-cols [16*cgrp, 16*cgrp+16); same cgrp%8 -> same XCD
  const int bg = blockIdx.x >> 6;     // batch rows [16*bg, 16*bg+16)
  const int rows0 = bg << 4;

  const int lane = tid & 63;
  const int wv = tid >> 6;            // wave = gate id: 0:i 1:f 2:o 3:g
  const int mcol = lane & 15;
  const int q = lane >> 4;

  f32x4 acc = {0.f, 0.f, 0.f, 0.f};
  // B-operand row in Wt for this lane: a_col = wv*1024 + cgrp*16 + (lane&15)
  const size_t wrow = ((size_t)(wv << 10) + (cgrp << 4) + mcol) * (size_t)KTOT;

  // ---- phase A: stage x_t rows (K 0..1023) as bf16 ----
  {
    const float4* x4 = (const float4*)x;
    for (int p = 0; p < 16; ++p) {
      int idx = (p << 8) + tid;
      int r = idx >> 8;               // 0..15
      int c4 = idx & 255;             // float4 within row (1024 floats)
      float4 v = x4[((size_t)(rows0 + r) * T_T + t) * 256 + c4];
      P4 pk;
      pk.h[0] = __float2bfloat16(v.x);
      pk.h[1] = __float2bfloat16(v.y);
      pk.h[2] = __float2bfloat16(v.z);
      pk.h[3] = __float2bfloat16(v.w);
      *(uint2*)&Alds[r][c4 << 2] = pk.u;
    }
  }
  __syncthreads();
  #pragma unroll 4
  for (int kk = 0; kk < 32; ++kk) {
    B8U a, b;
    a.u = *(const uint4*)&Alds[mcol][(kk << 5) + (q << 3)];
    b.u = *(const uint4*)(Wt + wrow + (kk << 5) + (q << 3));
    acc = __builtin_amdgcn_mfma_f32_16x16x32_bf16(a.v, b.v, acc, 0, 0, 0);
  }
  __syncthreads();
  // ---- phase B: stage h_{t-1} rows (K 1024..2047), already bf16 ----
  {
    const uint4* h4 = (const uint4*)hprev;  // 128 x uint4 per row
    for (int p = 0; p < 8; ++p) {
      int idx = (p << 8) + tid;
      int r = idx >> 7;               // 0..15
      int c8 = idx & 127;
      uint4 v = h4[(size_t)(rows0 + r) * 128 + c8];
      *(uint4*)&Alds[r][c8 << 3] = v;
    }
  }
  __syncthreads();
  #pragma unroll 4
  for (int kk = 0; kk < 32; ++kk) {
    B8U a, b;
    a.u = *(const uint4*)&Alds[mcol][(kk << 5) + (q << 3)];
    b.u = *(const uint4*)(Wt + wrow + 1024 + (kk << 5) + (q << 3));
    acc = __builtin_amdgcn_mfma_f32_16x16x32_bf16(a.v, b.v, acc, 0, 0, 0);
  }
  // C/D layout: D[row=(lane>>4)*4+i][col=lane&15]
  #pragma unroll
  for (int i = 0; i < 4; ++i)
    gtile[wv][(q << 2) + i][mcol] = acc[i];
  __syncthreads();
  // ---- epilogue: one thread per (row r, h-col j) of the 16x16 tile ----
  {
    int r = tid >> 4, j = tid & 15;
    int hcol = (cgrp << 4) + j;
    float av_i = gtile[0][r][j] + bias[hcol];
    float av_f = gtile[1][r][j] + bias[1024 + hcol];
    float av_o = gtile[2][r][j] + bias[2048 + hcol];
    float av_g = gtile[3][r][j] + bias[3072 + hcol];
    float iv = 1.f / (1.f + expf(-av_i));
    float fv = 1.f / (1.f + expf(-av_f));
    float ov = 1.f / (1.f + expf(-av_o));
    float gv = tanhf(av_g);
    int rg = rows0 + r;
    size_t cidx = (size_t)rg * 1024 + hcol;
    float cn = fv * cbuf[cidx] + iv * gv;
    cbuf[cidx] = cn;
    float hv = ov * tanhf(cn);
    out[((size_t)rg * T_T + t) * 1024 + hcol] = hv;
    hnext[cidx] = __float2bfloat16(hv);
  }
}

extern "C" void kernel_launch(void* const* d_in, const int* in_sizes, int n_in,
                              void* d_out, int out_size, void* d_ws, size_t ws_size,
                              hipStream_t stream) {
  const float* x    = (const float*)d_in[0];   // (64,512,1024)
  const float* h0   = (const float*)d_in[1];   // (64,1024)
  const float* Wx   = (const float*)d_in[2];   // (1024,4096)
  const float* Wh   = (const float*)d_in[3];   // (1024,4096)
  const float* bias = (const float*)d_in[4];   // (4096)
  float* out = (float*)d_out;                  // (64,512,1024) fp32

  char* ws = (char*)d_ws;
  __hip_bfloat16* Wt  = (__hip_bfloat16*)ws;                          // 16 MB
  __hip_bfloat16* hb0 = (__hip_bfloat16*)(ws + (size_t)16 * 1024 * 1024);
  __hip_bfloat16* hb1 = hb0 + 64 * 1024;
  float* cbuf = (float*)(hb1 + 64 * 1024);                            // total ~17.3 MB

  hipLaunchKernelGGL(prep_weights, dim3(2048), dim3(256), 0, stream, Wx, Wh, Wt);
  hipLaunchKernelGGL(prep_state, dim3(256), dim3(256), 0, stream, h0, hb0, cbuf);
  for (int t = 0; t < T_T; ++t) {
    __hip_bfloat16* hp = (t & 1) ? hb1 : hb0;
    __hip_bfloat16* hn = (t & 1) ? hb0 : hb1;
    hipLaunchKernelGGL(lstm_step, dim3(256), dim3(256), 0, stream,
                       x, bias, Wt, hp, hn, cbuf, out, t);
  }
}